// Round 4
// baseline (187.502 us; speedup 1.0000x reference)
//
#include <hip/hip_runtime.h>
#include <cstdint>

#define B_ 2
#define E_ 16
#define H_ 160
#define W_ 288
#define N_ 12
#define T_ 2
#define HW_ (H_*W_)        // 46080
#define P_ (T_*HW_)        // 92160
#define NINST (B_*N_)      // 24
#define NBINS 512          // err in [0,2] -> bin = min(511, err*256)
#define BINSCALE 256.0f

typedef unsigned long long u64;
typedef unsigned int u32;

__device__ inline float waveReduceSum(float v){
  #pragma unroll
  for(int o=32;o>0;o>>=1) v += __shfl_down(v, o, 64);
  return v;
}

// ---- Pass A: fused masked sum + sumsq + count; emb read ONCE per batch.
// Block = 768 threads = 12 waves; wave w handles instance (b, w); all 12 waves
// read the same 512-px emb chunk (L1/L2-resident after first touch).
__global__ __launch_bounds__(768) void k_stats(const float* __restrict__ mf1,
                                               const float* __restrict__ mf2,
                                               const int* __restrict__ gt,
                                               float* __restrict__ sumEmb,
                                               float* __restrict__ sumSq,
                                               float* __restrict__ cnt){
  int b    = blockIdx.x;
  int w    = threadIdx.x >> 6;       // 0..11 -> instance
  int lane = threadIdx.x & 63;
  int bn   = b*N_ + w;
  int pbase = blockIdx.y * 512;      // 512 | HW_ so t uniform
  int t = pbase / HW_;
  int rbase = pbase - t*HW_;
  const float* ep = (t ? mf2 : mf1) + (size_t)b*E_*HW_;
  const int*   gp = gt + (size_t)bn*P_ + pbase;

  float s[E_], q[E_]; float c = 0.f;
  #pragma unroll
  for(int e=0;e<E_;e++){ s[e]=0.f; q[e]=0.f; }
  #pragma unroll
  for(int it=0; it<8; ++it){
    int idx = it*64 + lane;
    int r = rbase + idx;
    float m = (float)gp[idx];
    c += m;
    #pragma unroll
    for(int e=0;e<E_;e++){
      float x = ep[(size_t)e*HW_ + r];
      float mx = m*x;
      s[e] += mx;
      q[e] = fmaf(mx, x, q[e]);
    }
  }
  #pragma unroll
  for(int e=0;e<E_;e++){
    float r1 = waveReduceSum(s[e]);
    float r2 = waveReduceSum(q[e]);
    if(lane==0){
      atomicAdd(&sumEmb[bn*E_ + e], r1);
      atomicAdd(&sumSq [bn*E_ + e], r2);
    }
  }
  float rc = waveReduceSum(c);
  if(lane==0) atomicAdd(&cnt[bn], rc);
}

// ---- Pass B: errors -> per-instance (count,label) histogram; emb read ONCE.
// Block = 512 px x all 12 instances. mean/var derived in-block from raw sums.
// err-sum per bin is replaced by bin-midpoint (error <= binwidth/2 * TV(jacc)
// ~= 2e-3, far under the 4e-2 threshold) so only ONE u32 LDS atomic per
// pixel-instance is needed.
__global__ __launch_bounds__(512) void k_err(const float* __restrict__ mf1,
                                             const float* __restrict__ mf2,
                                             const int* __restrict__ gt,
                                             const float* __restrict__ sumEmb,
                                             const float* __restrict__ sumSq,
                                             const float* __restrict__ cnt,
                                             u64* __restrict__ hist){
  __shared__ float smn[N_*E_], ssv[N_*E_];
  __shared__ u32 hcl[N_*NBINS];          // count<<16 | labelsum  (per-block <=512)
  int b = blockIdx.x;
  int tid = threadIdx.x;
  if(tid < N_*E_){
    float c  = cnt[b*N_ + (tid>>4)];
    float mu = sumEmb[b*N_*E_ + tid] / c;
    smn[tid] = mu;
    ssv[tid] = (sumSq[b*N_*E_ + tid] - c*mu*mu) / (c - 1.0f);
  }
  #pragma unroll
  for(int k=0;k<N_*NBINS/512;k++) hcl[k*512 + tid] = 0u;

  int p = blockIdx.y*512 + tid;
  int t = p / HW_;
  int r = p - t*HW_;
  const float* ep = (t ? mf2 : mf1) + (size_t)b*E_*HW_;
  float x[E_];
  #pragma unroll
  for(int e=0;e<E_;e++) x[e] = ep[(size_t)e*HW_ + r];
  __syncthreads();

  #pragma unroll
  for(int n=0;n<N_;n++){
    int bn = b*N_ + n;
    float d = 0.f;
    #pragma unroll
    for(int e=0;e<E_;e++){
      float df = x[e] - smn[n*E_+e];
      d = fmaf(df*df, ssv[n*E_+e], d);
    }
    float logits = 2.f*__expf(-0.5f*d) - 1.f;
    int   mi = gt[(size_t)bn*P_ + p];
    float ev = fmaxf(1.f - logits*(2.f*(float)mi - 1.f), 0.f);   // [0,2]
    int bin = min(NBINS-1, (int)(ev * BINSCALE));
    atomicAdd(&hcl[n*NBINS + bin], 0x10000u | (u32)mi);
  }
  __syncthreads();

  // skip-empty merge to global (count<<32 | label)
  for(int i=tid; i<N_*NBINS; i+=512){
    u32 v = hcl[i];
    if(v){
      int n = i / NBINS, bin = i - n*NBINS;
      atomicAdd(&hist[(size_t)(b*N_+n)*NBINS + bin],
                ((u64)(v>>16)<<32) | (u64)(v & 0xffffu));
    }
  }
}

// ---- Pass C: per-instance descending scan over bins + telescoped lovasz dot.
// contribution of a bin = midpoint * (jacc(end-state) - jacc(start-state)).
__global__ __launch_bounds__(256) void k_bins(const u64* __restrict__ hist,
                                              const float* __restrict__ cnt,
                                              float* __restrict__ out){
  const int PT = NBINS/256;   // 2 bins per thread (reversed order)
  int bn = blockIdx.x;
  const u64* h = hist + (size_t)bn*NBINS;
  int tid = threadIdx.x, lane = tid & 63, wave = tid >> 6;

  u64 loc[PT]; u64 s = 0;
  #pragma unroll
  for(int k=0;k<PT;k++){
    loc[k] = h[NBINS-1 - (tid*PT + k)];
    s += loc[k];
  }
  u64 sc = s;
  #pragma unroll
  for(int off=1;off<64;off<<=1){ u64 v = __shfl_up(sc, off, 64); if(lane>=off) sc += v; }
  __shared__ u64 wsum[4], wbase[4];
  if(lane==63) wsum[wave] = sc;
  __syncthreads();
  if(tid==0){
    u64 run = 0;
    #pragma unroll
    for(int w=0;w<4;w++){ wbase[w] = run; run += wsum[w]; }
  }
  __syncthreads();
  u64 excl = wbase[wave] + (sc - s);

  float G = cnt[bn];
  float lsum = 0.f;
  #pragma unroll
  for(int k=0;k<PT;k++){
    u64 lv = loc[k];
    u32 cb = (u32)(lv>>32), lb = (u32)(lv & 0xffffffffu);
    if(cb){
      int bin = NBINS-1 - (tid*PT + k);
      float mid = ((float)bin + 0.5f) * (1.0f/BINSCALE);
      float i0 = (float)(u32)(excl>>32);
      float c0 = (float)(u32)(excl & 0xffffffffu);
      float c1 = c0 + (float)lb;
      float jend   = 1.f - (G - c1)/(G + i0 + (float)cb - c1);
      float jstart = 1.f - (G - c0)/(G + i0 - c0);   // i0=0,c0=0 -> 0
      lsum += mid * (jend - jstart);
    }
    excl += lv;
  }

  __shared__ float rs[4];
  float tot = waveReduceSum(lsum);
  if(lane==0) rs[wave] = tot;
  __syncthreads();
  if(tid==0) atomicAdd(out, (rs[0]+rs[1]+rs[2]+rs[3]) * (1.0f/(float)NINST));
}

extern "C" void kernel_launch(void* const* d_in, const int* in_sizes, int n_in,
                              void* d_out, int out_size, void* d_ws, size_t ws_size,
                              hipStream_t stream){
  const float* mf1 = (const float*)d_in[0];
  const float* mf2 = (const float*)d_in[1];
  const int*   gt  = (const int*)d_in[2];
  float* out = (float*)d_out;

  // ws: [sumEmb 384f][cnt 24f][sumSq 384f] (8 KB header) then hist u64[24][512]
  float* sumEmb = (float*)d_ws;
  float* cnt    = sumEmb + 384;
  float* sumSq  = cnt + 24;
  u64*   hist   = (u64*)((char*)d_ws + 8192);
  size_t zbytes = 8192 + (size_t)NINST*NBINS*sizeof(u64);   // 8 KB + 96 KB

  hipMemsetAsync(d_ws, 0, zbytes, stream);
  hipMemsetAsync(d_out, 0, sizeof(float), stream);

  k_stats<<<dim3(B_, P_/512), 768, 0, stream>>>(mf1, mf2, gt, sumEmb, sumSq, cnt);
  k_err<<<dim3(B_, P_/512), 512, 0, stream>>>(mf1, mf2, gt, sumEmb, sumSq, cnt, hist);
  k_bins<<<NINST, 256, 0, stream>>>(hist, cnt, out);
}

// Round 5
// 140.872 us; speedup vs baseline: 1.3310x; 1.3310x over previous
//
#include <hip/hip_runtime.h>
#include <cstdint>

#define B_ 2
#define E_ 16
#define H_ 160
#define W_ 288
#define N_ 12
#define T_ 2
#define HW_ (H_*W_)        // 46080
#define P_ (T_*HW_)        // 92160
#define NINST (B_*N_)      // 24
#define NBINS 512          // err in [0,2] -> bin = min(511, err*256)
#define BINSCALE 256.0f

typedef unsigned long long u64;
typedef unsigned int u32;

__device__ inline float waveReduceSum(float v){
  #pragma unroll
  for(int o=32;o>0;o>>=1) v += __shfl_down(v, o, 64);
  return v;
}

// ---- Pass A: masked sum + sumsq + count. Per-instance blocks (redundant emb
// reads absorbed by L2/L3 -- measured faster than emb-once starvation), 720
// meaty blocks, float4/int4 vectorized (12 px/thread).
__global__ __launch_bounds__(256) void k_stats(const float* __restrict__ mf1,
                                               const float* __restrict__ mf2,
                                               const int* __restrict__ gt,
                                               float* __restrict__ sumEmb,
                                               float* __restrict__ sumSq,
                                               float* __restrict__ cnt){
  int bn = blockIdx.x;               // 0..23
  int b  = bn / N_;
  int pbase = blockIdx.y * 3072;     // 30 chunks of 3072 px
  const float* e1 = mf1 + (size_t)b*E_*HW_;
  const float* e2 = mf2 + (size_t)b*E_*HW_;
  const int*   gp = gt + (size_t)bn*P_;

  float s[E_], q[E_]; float c = 0.f;
  #pragma unroll
  for(int e=0;e<E_;e++){ s[e]=0.f; q[e]=0.f; }

  #pragma unroll
  for(int g=0; g<3; ++g){
    int p = pbase + g*1024 + threadIdx.x*4;      // aligned 4, never straddles HW_
    int t = (p >= HW_);
    int r = p - t*HW_;
    const float* ep = t ? e2 : e1;
    int4 m4 = *(const int4*)&gp[p];
    float m0 = (float)m4.x, m1 = (float)m4.y, m2 = (float)m4.z, m3 = (float)m4.w;
    c += m0+m1+m2+m3;
    #pragma unroll
    for(int e=0;e<E_;e++){
      float4 x = *(const float4*)&ep[(size_t)e*HW_ + r];
      float a0 = m0*x.x, a1 = m1*x.y, a2 = m2*x.z, a3 = m3*x.w;
      s[e] += a0+a1+a2+a3;
      q[e] = fmaf(a0, x.x, q[e]); q[e] = fmaf(a1, x.y, q[e]);
      q[e] = fmaf(a2, x.z, q[e]); q[e] = fmaf(a3, x.w, q[e]);
    }
  }
  __shared__ float red[2*E_+1];
  if(threadIdx.x < 2*E_+1) red[threadIdx.x] = 0.f;
  __syncthreads();
  int lane = threadIdx.x & 63;
  #pragma unroll
  for(int e=0;e<E_;e++){
    float r1 = waveReduceSum(s[e]);
    if(lane==0) atomicAdd(&red[e], r1);
    float r2 = waveReduceSum(q[e]);
    if(lane==0) atomicAdd(&red[E_+e], r2);
  }
  { float r = waveReduceSum(c); if(lane==0) atomicAdd(&red[2*E_], r); }
  __syncthreads();
  if(threadIdx.x < E_)         atomicAdd(&sumEmb[bn*E_ + threadIdx.x], red[threadIdx.x]);
  else if(threadIdx.x < 2*E_)  atomicAdd(&sumSq [bn*E_ + threadIdx.x - E_], red[threadIdx.x]);
  else if(threadIdx.x == 2*E_) atomicAdd(&cnt[bn], red[2*E_]);
}

// ---- tiny finalize: d = sum(x2*vA) + sum(x*vB) + vK  per instance ----------
__global__ void k_fin(const float* __restrict__ sumEmb, const float* __restrict__ sumSq,
                      const float* __restrict__ cnt,
                      float* __restrict__ vA, float* __restrict__ vB,
                      float* __restrict__ vK){
  __shared__ float lds[NINST*E_];
  int i = threadIdx.x;  // 384
  float c  = cnt[i>>4];
  float mu = sumEmb[i] / c;
  float v  = (sumSq[i] - c*mu*mu) / (c - 1.0f);
  vA[i] = v;
  vB[i] = -2.0f*mu*v;
  lds[i] = mu*mu*v;
  __syncthreads();
  if(i < NINST){
    float k = 0.f;
    #pragma unroll
    for(int e=0;e<E_;e++) k += lds[i*E_+e];
    vK[i] = k;
  }
}

// ---- Pass B: errors -> per-instance (count,label) histogram; emb read ONCE.
// Block = 256 px x all 12 instances of one batch. Per-instance constants come
// in via wave-uniform scalar loads (vA/vB/vK). Hot-bin LDS contention handled
// by a ballot leader-loop: one LDS atomic per distinct bin per wave.
__global__ __launch_bounds__(256) void k_err(const float* __restrict__ mf1,
                                             const float* __restrict__ mf2,
                                             const int* __restrict__ gt,
                                             const float* __restrict__ vA,
                                             const float* __restrict__ vB,
                                             const float* __restrict__ vK,
                                             u64* __restrict__ hist){
  __shared__ u32 hcl[N_*NBINS];          // count<<16 | labelsum (per-block <=256)
  int b = blockIdx.x;
  int tid = threadIdx.x;
  int lane = tid & 63;
  #pragma unroll
  for(int k=0;k<N_*NBINS/256;k++) hcl[k*256 + tid] = 0u;

  int p = blockIdx.y*256 + tid;          // 256 | HW_ so t uniform per block
  int t = (p >= HW_);
  int r = p - t*HW_;
  const float* ep = (t ? mf2 : mf1) + (size_t)b*E_*HW_;
  float x[E_], x2[E_];
  #pragma unroll
  for(int e=0;e<E_;e++) x[e] = ep[(size_t)e*HW_ + r];
  #pragma unroll
  for(int e=0;e<E_;e++) x2[e] = x[e]*x[e];
  __syncthreads();

  #pragma unroll
  for(int n=0;n<N_;n++){
    int bn = b*N_ + n;
    float d = vK[bn];
    #pragma unroll
    for(int e=0;e<E_;e++){
      d = fmaf(x2[e], vA[bn*E_+e], d);
      d = fmaf(x [e], vB[bn*E_+e], d);
    }
    float logits = 2.f*__expf(-0.5f*d) - 1.f;
    int   mi = gt[(size_t)bn*P_ + p];
    float ev = fmaxf(1.f - logits*(2.f*(float)mi - 1.f), 0.f);   // [0,2]
    int bin = min(NBINS-1, (int)(ev * BINSCALE));

    u64 mball = __ballot(mi != 0);
    u64 active = __ballot(1);
    while(active){
      int leader = __ffsll((unsigned long long)active) - 1;
      int lbin = __shfl(bin, leader, 64);
      u64 match = __ballot(bin == lbin);
      if(lane == leader){
        u32 cm = (u32)__popcll(match);
        u32 lm = (u32)__popcll(match & mball);
        atomicAdd(&hcl[n*NBINS + lbin], (cm<<16) | lm);
      }
      active &= ~match;
    }
  }
  __syncthreads();

  for(int i=tid; i<N_*NBINS; i+=256){
    u32 v = hcl[i];
    if(v){
      int n = i / NBINS, bin = i - n*NBINS;
      atomicAdd(&hist[(size_t)(b*N_+n)*NBINS + bin],
                ((u64)(v>>16)<<32) | (u64)(v & 0xffffu));
    }
  }
}

// ---- Pass C: per-instance descending scan over bins + telescoped lovasz dot.
__global__ __launch_bounds__(256) void k_bins(const u64* __restrict__ hist,
                                              const float* __restrict__ cnt,
                                              float* __restrict__ out){
  const int PT = NBINS/256;   // 2 bins per thread (reversed order)
  int bn = blockIdx.x;
  const u64* h = hist + (size_t)bn*NBINS;
  int tid = threadIdx.x, lane = tid & 63, wave = tid >> 6;

  u64 loc[PT]; u64 s = 0;
  #pragma unroll
  for(int k=0;k<PT;k++){
    loc[k] = h[NBINS-1 - (tid*PT + k)];
    s += loc[k];
  }
  u64 sc = s;
  #pragma unroll
  for(int off=1;off<64;off<<=1){ u64 v = __shfl_up(sc, off, 64); if(lane>=off) sc += v; }
  __shared__ u64 wsum[4], wbase[4];
  if(lane==63) wsum[wave] = sc;
  __syncthreads();
  if(tid==0){
    u64 run = 0;
    #pragma unroll
    for(int w=0;w<4;w++){ wbase[w] = run; run += wsum[w]; }
  }
  __syncthreads();
  u64 excl = wbase[wave] + (sc - s);

  float G = cnt[bn];
  float lsum = 0.f;
  #pragma unroll
  for(int k=0;k<PT;k++){
    u64 lv = loc[k];
    u32 cb = (u32)(lv>>32), lb = (u32)(lv & 0xffffffffu);
    if(cb){
      int bin = NBINS-1 - (tid*PT + k);
      float mid = ((float)bin + 0.5f) * (1.0f/BINSCALE);
      float i0 = (float)(u32)(excl>>32);
      float c0 = (float)(u32)(excl & 0xffffffffu);
      float c1 = c0 + (float)lb;
      float jend   = 1.f - (G - c1)/(G + i0 + (float)cb - c1);
      float jstart = 1.f - (G - c0)/(G + i0 - c0);   // i0=0,c0=0 -> 0
      lsum += mid * (jend - jstart);
    }
    excl += lv;
  }

  __shared__ float rs[4];
  float tot = waveReduceSum(lsum);
  if(lane==0) rs[wave] = tot;
  __syncthreads();
  if(tid==0) atomicAdd(out, (rs[0]+rs[1]+rs[2]+rs[3]) * (1.0f/(float)NINST));
}

extern "C" void kernel_launch(void* const* d_in, const int* in_sizes, int n_in,
                              void* d_out, int out_size, void* d_ws, size_t ws_size,
                              hipStream_t stream){
  const float* mf1 = (const float*)d_in[0];
  const float* mf2 = (const float*)d_in[1];
  const int*   gt  = (const int*)d_in[2];
  float* out = (float*)d_out;

  // ws: [sumEmb 384f][cnt 24f][sumSq 384f] in first 8 KB (zeroed),
  //     hist u64[24][512] at +8 KB (zeroed),
  //     consts vA[384] vB[384] vK[24] after hist (written by k_fin).
  float* sumEmb = (float*)d_ws;
  float* cnt    = sumEmb + 384;
  float* sumSq  = cnt + 24;
  u64*   hist   = (u64*)((char*)d_ws + 8192);
  float* vA     = (float*)((char*)hist + (size_t)NINST*NBINS*sizeof(u64));
  float* vB     = vA + NINST*E_;
  float* vK     = vB + NINST*E_;
  size_t zbytes = 8192 + (size_t)NINST*NBINS*sizeof(u64);   // 8 KB + 96 KB

  hipMemsetAsync(d_ws, 0, zbytes, stream);
  hipMemsetAsync(d_out, 0, sizeof(float), stream);

  k_stats<<<dim3(NINST, P_/3072), 256, 0, stream>>>(mf1, mf2, gt, sumEmb, sumSq, cnt);
  k_fin<<<1, 384, 0, stream>>>(sumEmb, sumSq, cnt, vA, vB, vK);
  k_err<<<dim3(B_, P_/256), 256, 0, stream>>>(mf1, mf2, gt, vA, vB, vK, hist);
  k_bins<<<NINST, 256, 0, stream>>>(hist, cnt, out);
}